// Round 1
// 3467.682 us; speedup vs baseline: 1.1058x; 1.1058x over previous
//
#include <hip/hip_runtime.h>
#include <hip/hip_bf16.h>
#include <math.h>

#define L_SEQ 512
#define N_B   64
#define H_D   512
#define M_TOT (L_SEQ * N_B)   // 32768

typedef unsigned short u16;
typedef unsigned long long u64;
typedef __attribute__((ext_vector_type(8))) short short8;
typedef __attribute__((ext_vector_type(4))) float f32x4;
typedef __attribute__((ext_vector_type(4))) int i32x4;

__device__ __forceinline__ u16 f2bf(float f) {
    unsigned int u = __builtin_bit_cast(unsigned int, f);
    u = u + 0x7fffu + ((u >> 16) & 1u);
    return (u16)(u >> 16);
}

__device__ __forceinline__ float fast_tanh(float x) {
    float e = __expf(2.0f * x);
    return 1.0f - 2.0f / (e + 1.0f);
}

__device__ __forceinline__ void st_h(u16* p, u16 v) {
    __hip_atomic_store(p, v, __ATOMIC_RELAXED, __HIP_MEMORY_SCOPE_AGENT);
}
__device__ __forceinline__ void st_flag(int* p, int v) {
    __hip_atomic_store(p, v, __ATOMIC_RELAXED, __HIP_MEMORY_SCOPE_AGENT);
}
// all 16 producer words (layout [c][4w]) must reach >= need
// RELAXED polls on purpose: an acquire here would buffer_inv L2 every
// poll and destroy the cached-h reuse. Data freshness argument: slots
// are write-once (sc1 write-through to L3) and first-touched by any
// consumer only after the flag trips, so a cached load can never hit a
// stale line within this run; cross-run lines are killed by the entry
// acquire fence in k_rec_fused.
__device__ __forceinline__ void wait_flags16(const int* fl, int w, int need) {
    const int l = threadIdx.x & 63;
    const int* p = fl + (l & 15) * 4 + w;
    while (true) {
        int v = __hip_atomic_load(p, __ATOMIC_RELAXED, __HIP_MEMORY_SCOPE_AGENT);
        if (__all(v >= need)) break;
    }
    asm volatile("" ::: "memory");
}
// combined wait: flags0 (16 words) >= t+2 AND flags1 (32 words) >= t+1
__device__ __forceinline__ void wait_flags_l1(const int* f0, const int* f1, int w, int t) {
    const int l = threadIdx.x & 63;
    const int* p;
    int need;
    if (l < 16)      { p = f0 + l * 4 + w;        need = t + 2; }
    else if (l < 48) { p = f1 + (l - 16) * 4 + w; need = t + 1; }
    else             { p = f0 + w;                need = 0;     }
    while (true) {
        int v = __hip_atomic_load(p, __ATOMIC_RELAXED, __HIP_MEMORY_SCOPE_AGENT);
        if (__all(v >= need)) break;
    }
    asm volatile("" ::: "memory");
}

// 16 CACHED 16B loads (512B of one row) + single drain.
// No sc1: these go through L1/L2 so the ~32x duplicated h reads across
// consumer blocks dedup in each XCD's L2 instead of each being a
// device-coherent transaction.
#define LD16(f, p)                                                          \
  asm volatile(                                                             \
    "global_load_dwordx4 %0, %16, off\n\t"                                  \
    "global_load_dwordx4 %1, %16, off offset:64\n\t"                        \
    "global_load_dwordx4 %2, %16, off offset:128\n\t"                       \
    "global_load_dwordx4 %3, %16, off offset:192\n\t"                       \
    "global_load_dwordx4 %4, %16, off offset:256\n\t"                       \
    "global_load_dwordx4 %5, %16, off offset:320\n\t"                       \
    "global_load_dwordx4 %6, %16, off offset:384\n\t"                       \
    "global_load_dwordx4 %7, %16, off offset:448\n\t"                       \
    "global_load_dwordx4 %8, %16, off offset:512\n\t"                       \
    "global_load_dwordx4 %9, %16, off offset:576\n\t"                       \
    "global_load_dwordx4 %10, %16, off offset:640\n\t"                      \
    "global_load_dwordx4 %11, %16, off offset:704\n\t"                      \
    "global_load_dwordx4 %12, %16, off offset:768\n\t"                      \
    "global_load_dwordx4 %13, %16, off offset:832\n\t"                      \
    "global_load_dwordx4 %14, %16, off offset:896\n\t"                      \
    "global_load_dwordx4 %15, %16, off offset:960\n\t"                      \
    "s_waitcnt vmcnt(0)"                                                    \
    : "=&v"(f[0]), "=&v"(f[1]), "=&v"(f[2]), "=&v"(f[3]),                   \
      "=&v"(f[4]), "=&v"(f[5]), "=&v"(f[6]), "=&v"(f[7]),                   \
      "=&v"(f[8]), "=&v"(f[9]), "=&v"(f[10]), "=&v"(f[11]),                 \
      "=&v"(f[12]), "=&v"(f[13]), "=&v"(f[14]), "=&v"(f[15])                \
    : "v"(p) : "memory")

// 32 cached loads from two rows in one batch (layer 1), single drain
#define LD16X2(f, g, p0, p1)                                                \
  asm volatile(                                                             \
    "global_load_dwordx4 %0, %32, off\n\t"                                  \
    "global_load_dwordx4 %16, %33, off\n\t"                                 \
    "global_load_dwordx4 %1, %32, off offset:64\n\t"                        \
    "global_load_dwordx4 %17, %33, off offset:64\n\t"                       \
    "global_load_dwordx4 %2, %32, off offset:128\n\t"                       \
    "global_load_dwordx4 %18, %33, off offset:128\n\t"                      \
    "global_load_dwordx4 %3, %32, off offset:192\n\t"                       \
    "global_load_dwordx4 %19, %33, off offset:192\n\t"                      \
    "global_load_dwordx4 %4, %32, off offset:256\n\t"                       \
    "global_load_dwordx4 %20, %33, off offset:256\n\t"                      \
    "global_load_dwordx4 %5, %32, off offset:320\n\t"                       \
    "global_load_dwordx4 %21, %33, off offset:320\n\t"                      \
    "global_load_dwordx4 %6, %32, off offset:384\n\t"                       \
    "global_load_dwordx4 %22, %33, off offset:384\n\t"                      \
    "global_load_dwordx4 %7, %32, off offset:448\n\t"                       \
    "global_load_dwordx4 %23, %33, off offset:448\n\t"                      \
    "global_load_dwordx4 %8, %32, off offset:512\n\t"                       \
    "global_load_dwordx4 %24, %33, off offset:512\n\t"                      \
    "global_load_dwordx4 %9, %32, off offset:576\n\t"                       \
    "global_load_dwordx4 %25, %33, off offset:576\n\t"                      \
    "global_load_dwordx4 %10, %32, off offset:640\n\t"                      \
    "global_load_dwordx4 %26, %33, off offset:640\n\t"                      \
    "global_load_dwordx4 %11, %32, off offset:704\n\t"                      \
    "global_load_dwordx4 %27, %33, off offset:704\n\t"                      \
    "global_load_dwordx4 %12, %32, off offset:768\n\t"                      \
    "global_load_dwordx4 %28, %33, off offset:768\n\t"                      \
    "global_load_dwordx4 %13, %32, off offset:832\n\t"                      \
    "global_load_dwordx4 %29, %33, off offset:832\n\t"                      \
    "global_load_dwordx4 %14, %32, off offset:896\n\t"                      \
    "global_load_dwordx4 %30, %33, off offset:896\n\t"                      \
    "global_load_dwordx4 %15, %32, off offset:960\n\t"                      \
    "global_load_dwordx4 %31, %33, off offset:960\n\t"                      \
    "s_waitcnt vmcnt(0)"                                                    \
    : "=&v"(f[0]), "=&v"(f[1]), "=&v"(f[2]), "=&v"(f[3]),                   \
      "=&v"(f[4]), "=&v"(f[5]), "=&v"(f[6]), "=&v"(f[7]),                   \
      "=&v"(f[8]), "=&v"(f[9]), "=&v"(f[10]), "=&v"(f[11]),                 \
      "=&v"(f[12]), "=&v"(f[13]), "=&v"(f[14]), "=&v"(f[15]),               \
      "=&v"(g[0]), "=&v"(g[1]), "=&v"(g[2]), "=&v"(g[3]),                   \
      "=&v"(g[4]), "=&v"(g[5]), "=&v"(g[6]), "=&v"(g[7]),                   \
      "=&v"(g[8]), "=&v"(g[9]), "=&v"(g[10]), "=&v"(g[11]),                 \
      "=&v"(g[12]), "=&v"(g[13]), "=&v"(g[14]), "=&v"(g[15])                \
    : "v"(p0), "v"(p1) : "memory")

#define WAITVM asm volatile("s_waitcnt vmcnt(0)" ::: "memory")

// ---- prep: fp32->bf16 conversions, bias sums, flag zeroing ----
__global__ void k_prep(const float* __restrict__ x,
                       const float* __restrict__ w0ih, const float* __restrict__ w0hh,
                       const float* __restrict__ b0i,  const float* __restrict__ b0h,
                       const float* __restrict__ w1ih, const float* __restrict__ w1hh,
                       const float* __restrict__ b1i,  const float* __restrict__ b1h,
                       u16* __restrict__ xb,
                       u16* __restrict__ w0ihb, u16* __restrict__ w0hhb,
                       u16* __restrict__ w1ihb, u16* __restrict__ w1hhb,
                       float* __restrict__ bias0, float* __restrict__ bias1,
                       int* __restrict__ flags)
{
    const int stride = gridDim.x * blockDim.x;
    const int tid = blockIdx.x * blockDim.x + threadIdx.x;
    for (int i = tid; i < M_TOT * H_D / 4; i += stride) {
        const float4 v = ((const float4*)x)[i];
        ushort4 o;
        o.x = f2bf(v.x); o.y = f2bf(v.y); o.z = f2bf(v.z); o.w = f2bf(v.w);
        ((ushort4*)xb)[i] = o;
    }
    for (int i = tid; i < H_D * H_D; i += stride) {
        w0ihb[i] = f2bf(w0ih[i]);
        w0hhb[i] = f2bf(w0hh[i]);
        w1ihb[i] = f2bf(w1ih[i]);
        w1hhb[i] = f2bf(w1hh[i]);
    }
    if (tid < H_D) {
        bias0[tid] = b0i[tid] + b0h[tid];
        bias1[tid] = b1i[tid] + b1h[tid];
    }
    if (tid < 192) flags[tid] = 0;
}

// ---- big parallel GEMM: out[M,512] = A @ W^T + bias (bf16 MFMA) ----
__global__ __launch_bounds__(256)
void k_gemm(const u16* __restrict__ A, const u16* __restrict__ W,
            const float* __restrict__ bias, float* __restrict__ out)
{
    __shared__ u16 As[128][40];
    __shared__ u16 Ws[128][40];
    const int m0 = blockIdx.x * 128;
    const int n0 = blockIdx.y * 128;
    const int tid = threadIdx.x;
    const int w = tid >> 6, l = tid & 63, q = l >> 4, lr = l & 15;
    const int mw = (w >> 1) * 64, nw = (w & 1) * 64;
    const int skg = (tid & 3) * 8;
    const int smr = tid >> 2;

    f32x4 acc[4][4];
    #pragma unroll
    for (int i = 0; i < 4; ++i)
        #pragma unroll
        for (int j = 0; j < 4; ++j)
            acc[i][j] = (f32x4){0.f, 0.f, 0.f, 0.f};

    for (int kk = 0; kk < H_D; kk += 32) {
        *(uint4*)&As[smr][skg]      = *(const uint4*)(A + (size_t)(m0 + smr) * H_D + kk + skg);
        *(uint4*)&As[smr + 64][skg] = *(const uint4*)(A + (size_t)(m0 + smr + 64) * H_D + kk + skg);
        *(uint4*)&Ws[smr][skg]      = *(const uint4*)(W + (size_t)(n0 + smr) * H_D + kk + skg);
        *(uint4*)&Ws[smr + 64][skg] = *(const uint4*)(W + (size_t)(n0 + smr + 64) * H_D + kk + skg);
        __syncthreads();
        short8 af[4], bf[4];
        #pragma unroll
        for (int rt = 0; rt < 4; ++rt) af[rt] = *(const short8*)&As[mw + rt*16 + lr][q*8];
        #pragma unroll
        for (int nt = 0; nt < 4; ++nt) bf[nt] = *(const short8*)&Ws[nw + nt*16 + lr][q*8];
        #pragma unroll
        for (int rt = 0; rt < 4; ++rt)
            #pragma unroll
            for (int nt = 0; nt < 4; ++nt)
                acc[rt][nt] = __builtin_amdgcn_mfma_f32_16x16x32_bf16(af[rt], bf[nt], acc[rt][nt], 0, 0, 0);
        __syncthreads();
    }
    #pragma unroll
    for (int nt = 0; nt < 4; ++nt) {
        const int col = n0 + nw + nt*16 + lr;
        const float bv = bias[col];
        #pragma unroll
        for (int rt = 0; rt < 4; ++rt) {
            #pragma unroll
            for (int r = 0; r < 4; ++r) {
                const int row = m0 + mw + rt*16 + q*4 + r;
                out[(size_t)row * H_D + col] = acc[rt][nt][r] + bv;
            }
        }
    }
}

// ---- fused 2-layer recurrence, pipelined across layers ----
// blocks 0..15: layer 0 (32-col slices).  blocks 16..47: layer 1 (16-col slices).
// hbuf slot s holds h[t = s-1]; slot 0 = h_init. flags [c][4w] = slots published.
// Protocol: h stores are sc1 (write-through to the device coherence point);
// flags are sc1 relaxed-polled; h LOADS are normal cached loads (slots are
// write-once, first-touched only after the flag). Entry acquire fence kills
// any pre-kernel (previous-iteration / xb-aliased) lines in L1/L2.
__global__ __launch_bounds__(256, 1)
void k_rec_fused(const u16* __restrict__ Whh0, const u16* __restrict__ Wih1,
                 const u16* __restrict__ Whh1,
                 const float* __restrict__ h_init,
                 const float* __restrict__ pre0,
                 const float* __restrict__ bias1,
                 u16* __restrict__ h0buf, u16* __restrict__ h1buf,
                 float* __restrict__ out, float* __restrict__ hn,
                 int* __restrict__ flags0, int* __restrict__ flags1)
{
    // One-shot agent-scope acquire: emits buffer_inv sc1 (invalidate L1 +
    // XCD-local L2) so no stale pre-kernel line can satisfy our cached h
    // loads. Must NOT appear in the poll loops (would kill L2 reuse).
    (void)__hip_atomic_load(flags0, __ATOMIC_ACQUIRE, __HIP_MEMORY_SCOPE_AGENT);

    const int tid = threadIdx.x;
    const int w = tid >> 6, l = tid & 63, q = l >> 4, lr = l & 15;
    const int r0 = w * 16;
    const int m = r0 + lr;

    if (blockIdx.x < 16) {
        // ================= layer 0: 32 columns =================
        const int c = blockIdx.x;
        const int nbase = c * 32;
        short8 breg[16][2];
        #pragma unroll
        for (int kt = 0; kt < 16; ++kt)
            #pragma unroll
            for (int nt = 0; nt < 2; ++nt)
                breg[kt][nt] = *(const short8*)(Whh0 + (size_t)(nbase + nt*16 + lr) * H_D + kt*32 + q*8);

        // stage 0: publish h_init slot 0 (our 16 rows x 32 cols)
        #pragma unroll
        for (int j = 0; j < 8; ++j) {
            int idx = l * 8 + j;
            int row = r0 + (idx >> 5);
            int col = nbase + (idx & 31);
            st_h(h0buf + (size_t)row * H_D + col, f2bf(h_init[row * H_D + col]));
        }
        WAITVM;
        if (l == 0) st_flag(flags0 + c*4 + w, 1);

        for (int t = 0; t < L_SEQ; ++t) {
            f32x4 acc0, acc1;
            const float* pt = pre0 + (size_t)t * (N_B * H_D);
            #pragma unroll
            for (int r = 0; r < 4; ++r) {
                acc0[r] = pt[(size_t)(r0 + q*4 + r) * H_D + nbase + lr];
                acc1[r] = pt[(size_t)(r0 + q*4 + r) * H_D + nbase + 16 + lr];
            }
            wait_flags16(flags0, w, t + 1);
            const u16* hs = h0buf + ((size_t)t * N_B + m) * H_D + q*8;
            i32x4 f[16];
            LD16(f, hs);
            #pragma unroll
            for (int kt = 0; kt < 16; ++kt) {
                short8 a = __builtin_bit_cast(short8, f[kt]);
                acc0 = __builtin_amdgcn_mfma_f32_16x16x32_bf16(a, breg[kt][0], acc0, 0, 0, 0);
                acc1 = __builtin_amdgcn_mfma_f32_16x16x32_bf16(a, breg[kt][1], acc1, 0, 0, 0);
            }
            float v0[4], v1[4];
            unsigned hv[8];
            #pragma unroll
            for (int r = 0; r < 4; ++r) {
                v0[r] = fast_tanh(acc0[r]);
                v1[r] = fast_tanh(acc1[r]);
                hv[2*r]   = f2bf(v0[r]);
                hv[2*r+1] = f2bf(v1[r]);
            }
            u16* hd = h0buf + (size_t)(t+1) * (N_B * H_D) + (size_t)(r0 + q*4) * H_D + nbase + lr;
            asm volatile(
                "global_store_short %8, %0, off sc1\n\t"
                "global_store_short %8, %1, off offset:32 sc1\n\t"
                "global_store_short %8, %2, off offset:1024 sc1\n\t"
                "global_store_short %8, %3, off offset:1056 sc1\n\t"
                "global_store_short %8, %4, off offset:2048 sc1\n\t"
                "global_store_short %8, %5, off offset:2080 sc1\n\t"
                "global_store_short %8, %6, off offset:3072 sc1\n\t"
                "global_store_short %8, %7, off offset:3104 sc1"
                :: "v"(hv[0]), "v"(hv[1]), "v"(hv[2]), "v"(hv[3]),
                   "v"(hv[4]), "v"(hv[5]), "v"(hv[6]), "v"(hv[7]), "v"(hd)
                : "memory");
            WAITVM;
            if (l == 0) st_flag(flags0 + c*4 + w, t + 2);
            if (t == L_SEQ - 1) {
                #pragma unroll
                for (int r = 0; r < 4; ++r) {
                    int row = r0 + q*4 + r;
                    hn[(size_t)row * H_D + nbase + lr]      = v0[r];
                    hn[(size_t)row * H_D + nbase + 16 + lr] = v1[r];
                }
            }
        }
    } else {
        // ================= layer 1: 16 columns =================
        const int c = blockIdx.x - 16;
        const int nbase = c * 16;
        short8 bregI[16], bregH[16];
        #pragma unroll
        for (int kt = 0; kt < 16; ++kt) {
            bregI[kt] = *(const short8*)(Wih1 + (size_t)(nbase + lr) * H_D + kt*32 + q*8);
            bregH[kt] = *(const short8*)(Whh1 + (size_t)(nbase + lr) * H_D + kt*32 + q*8);
        }
        const float bv = bias1[nbase + lr];

        const float* hi1 = h_init + N_B * H_D;
        #pragma unroll
        for (int j = 0; j < 4; ++j) {
            int idx = l * 4 + j;
            int row = r0 + (idx >> 4);
            int col = nbase + (idx & 15);
            st_h(h1buf + (size_t)row * H_D + col, f2bf(hi1[row * H_D + col]));
        }
        WAITVM;
        if (l == 0) st_flag(flags1 + c*4 + w, 1);

        for (int t = 0; t < L_SEQ; ++t) {
            wait_flags_l1(flags0, flags1, w, t);
            const u16* p0 = h0buf + ((size_t)(t+1) * N_B + m) * H_D + q*8;
            const u16* p1 = h1buf + ((size_t)t     * N_B + m) * H_D + q*8;
            i32x4 f[16], g[16];
            LD16X2(f, g, p0, p1);
            f32x4 accI = {bv, bv, bv, bv};
            f32x4 accH = {0.f, 0.f, 0.f, 0.f};
            #pragma unroll
            for (int kt = 0; kt < 16; ++kt) {
                accI = __builtin_amdgcn_mfma_f32_16x16x32_bf16(__builtin_bit_cast(short8, f[kt]), bregI[kt], accI, 0, 0, 0);
                accH = __builtin_amdgcn_mfma_f32_16x16x32_bf16(__builtin_bit_cast(short8, g[kt]), bregH[kt], accH, 0, 0, 0);
            }
            float v[4];
            unsigned hv[4];
            #pragma unroll
            for (int r = 0; r < 4; ++r) {
                v[r] = fast_tanh(accI[r] + accH[r]);
                hv[r] = f2bf(v[r]);
            }
            u16* hd = h1buf + (size_t)(t+1) * (N_B * H_D) + (size_t)(r0 + q*4) * H_D + nbase + lr;
            asm volatile(
                "global_store_short %4, %0, off sc1\n\t"
                "global_store_short %4, %1, off offset:1024 sc1\n\t"
                "global_store_short %4, %2, off offset:2048 sc1\n\t"
                "global_store_short %4, %3, off offset:3072 sc1"
                :: "v"(hv[0]), "v"(hv[1]), "v"(hv[2]), "v"(hv[3]), "v"(hd)
                : "memory");
            WAITVM;
            if (l == 0) st_flag(flags1 + c*4 + w, t + 2);
            float* od = out + (size_t)t * (N_B * H_D);
            #pragma unroll
            for (int r = 0; r < 4; ++r) {
                int row = r0 + q*4 + r;
                od[(size_t)row * H_D + nbase + lr] = v[r];
                if (t == L_SEQ - 1)
                    hn[(size_t)(N_B + row) * H_D + nbase + lr] = v[r];
            }
        }
    }
}

extern "C" void kernel_launch(void* const* d_in, const int* in_sizes, int n_in,
                              void* d_out, int out_size, void* d_ws, size_t ws_size,
                              hipStream_t stream)
{
    (void)in_sizes; (void)n_in; (void)out_size; (void)ws_size;
    const float* x    = (const float*)d_in[0];
    const float* h0   = (const float*)d_in[1];
    const float* w0ih = (const float*)d_in[2];
    const float* w0hh = (const float*)d_in[3];
    const float* b0i  = (const float*)d_in[4];
    const float* b0h  = (const float*)d_in[5];
    const float* w1ih = (const float*)d_in[6];
    const float* w1hh = (const float*)d_in[7];
    const float* b1i  = (const float*)d_in[8];
    const float* b1h  = (const float*)d_in[9];
    float* out = (float*)d_out;
    float* hn  = out + (size_t)M_TOT * H_D;

    char* ws = (char*)d_ws;
    size_t off = 0;
    u16* w0ihb = (u16*)(ws + off);   off += (size_t)H_D * H_D * 2;
    u16* w0hhb = (u16*)(ws + off);   off += (size_t)H_D * H_D * 2;
    u16* w1ihb = (u16*)(ws + off);   off += (size_t)H_D * H_D * 2;
    u16* w1hhb = (u16*)(ws + off);   off += (size_t)H_D * H_D * 2;
    float* bias0 = (float*)(ws + off); off += H_D * 4;
    float* bias1 = (float*)(ws + off); off += H_D * 4;
    int* flags   = (int*)(ws + off);   off += 256 * 4;
    int* flags0  = flags;
    int* flags1  = flags + 64;
    u16* h0buf   = (u16*)(ws + off);   off += (size_t)(L_SEQ + 1) * N_B * H_D * 2;
    float* pre0  = (float*)(ws + off); off += (size_t)M_TOT * H_D * 4;
    u16* h1buf   = (u16*)(ws + off);   off += (size_t)(L_SEQ + 1) * N_B * H_D * 2;
    u16* xb      = h1buf;   // xb dead after k_gemm; aliases h1buf

    k_prep<<<2048, 256, 0, stream>>>(x, w0ih, w0hh, b0i, b0h, w1ih, w1hh, b1i, b1h,
                                     xb, w0ihb, w0hhb, w1ihb, w1hhb,
                                     bias0, bias1, flags);
    k_gemm<<<dim3(M_TOT/128, H_D/128), 256, 0, stream>>>(xb, w0ihb, bias0, pre0);
    k_rec_fused<<<48, 256, 0, stream>>>(w0hhb, w1ihb, w1hhb, h0, pre0, bias1,
                                        h0buf, h1buf, out, hn, flags0, flags1);
}

// Round 2
// 3047.836 us; speedup vs baseline: 1.2581x; 1.1378x over previous
//
#include <hip/hip_runtime.h>
#include <hip/hip_bf16.h>
#include <math.h>

#define L_SEQ 512
#define N_B   64
#define H_D   512
#define M_TOT (L_SEQ * N_B)   // 32768

typedef unsigned short u16;
typedef unsigned long long u64;
typedef __attribute__((ext_vector_type(8))) short short8;
typedef __attribute__((ext_vector_type(4))) float f32x4;
typedef __attribute__((ext_vector_type(4))) int i32x4;
typedef __attribute__((ext_vector_type(2))) int i32x2;

__device__ __forceinline__ u16 f2bf(float f) {
    unsigned int u = __builtin_bit_cast(unsigned int, f);
    u = u + 0x7fffu + ((u >> 16) & 1u);
    return (u16)(u >> 16);
}

__device__ __forceinline__ float fast_tanh(float x) {
    float e = __expf(2.0f * x);
    return 1.0f - 2.0f / (e + 1.0f);
}

__device__ __forceinline__ void st_h(u16* p, u16 v) {
    __hip_atomic_store(p, v, __ATOMIC_RELAXED, __HIP_MEMORY_SCOPE_AGENT);
}
__device__ __forceinline__ void st_flag(int* p, int v) {
    __hip_atomic_store(p, v, __ATOMIC_RELAXED, __HIP_MEMORY_SCOPE_AGENT);
}

// 16 CACHED 16B loads (512B of one row) + single drain.
// Correctness of cached loads: h slots are write-once (sc1 write-through to
// the coherence point), consumers first touch a slot's lines only after the
// per-block flag trips, and slot lines are 64B-pure. Entry acquire fence
// kills pre-kernel stale lines (incl. the xb/h1buf alias from k_gemm).
#define LD16(f, p)                                                          \
  asm volatile(                                                             \
    "global_load_dwordx4 %0, %16, off\n\t"                                  \
    "global_load_dwordx4 %1, %16, off offset:64\n\t"                        \
    "global_load_dwordx4 %2, %16, off offset:128\n\t"                       \
    "global_load_dwordx4 %3, %16, off offset:192\n\t"                       \
    "global_load_dwordx4 %4, %16, off offset:256\n\t"                       \
    "global_load_dwordx4 %5, %16, off offset:320\n\t"                       \
    "global_load_dwordx4 %6, %16, off offset:384\n\t"                       \
    "global_load_dwordx4 %7, %16, off offset:448\n\t"                       \
    "global_load_dwordx4 %8, %16, off offset:512\n\t"                       \
    "global_load_dwordx4 %9, %16, off offset:576\n\t"                       \
    "global_load_dwordx4 %10, %16, off offset:640\n\t"                      \
    "global_load_dwordx4 %11, %16, off offset:704\n\t"                      \
    "global_load_dwordx4 %12, %16, off offset:768\n\t"                      \
    "global_load_dwordx4 %13, %16, off offset:832\n\t"                      \
    "global_load_dwordx4 %14, %16, off offset:896\n\t"                      \
    "global_load_dwordx4 %15, %16, off offset:960\n\t"                      \
    "s_waitcnt vmcnt(0)"                                                    \
    : "=&v"(f[0]), "=&v"(f[1]), "=&v"(f[2]), "=&v"(f[3]),                   \
      "=&v"(f[4]), "=&v"(f[5]), "=&v"(f[6]), "=&v"(f[7]),                   \
      "=&v"(f[8]), "=&v"(f[9]), "=&v"(f[10]), "=&v"(f[11]),                 \
      "=&v"(f[12]), "=&v"(f[13]), "=&v"(f[14]), "=&v"(f[15])                \
    : "v"(p) : "memory")

// 32 cached loads from two rows in one batch (layer 1), single drain
#define LD16X2(f, g, p0, p1)                                                \
  asm volatile(                                                             \
    "global_load_dwordx4 %0, %32, off\n\t"                                  \
    "global_load_dwordx4 %16, %33, off\n\t"                                 \
    "global_load_dwordx4 %1, %32, off offset:64\n\t"                        \
    "global_load_dwordx4 %17, %33, off offset:64\n\t"                       \
    "global_load_dwordx4 %2, %32, off offset:128\n\t"                       \
    "global_load_dwordx4 %18, %33, off offset:128\n\t"                      \
    "global_load_dwordx4 %3, %32, off offset:192\n\t"                       \
    "global_load_dwordx4 %19, %33, off offset:192\n\t"                      \
    "global_load_dwordx4 %4, %32, off offset:256\n\t"                       \
    "global_load_dwordx4 %20, %33, off offset:256\n\t"                      \
    "global_load_dwordx4 %5, %32, off offset:320\n\t"                       \
    "global_load_dwordx4 %21, %33, off offset:320\n\t"                      \
    "global_load_dwordx4 %6, %32, off offset:384\n\t"                       \
    "global_load_dwordx4 %22, %33, off offset:384\n\t"                      \
    "global_load_dwordx4 %7, %32, off offset:448\n\t"                       \
    "global_load_dwordx4 %23, %33, off offset:448\n\t"                      \
    "global_load_dwordx4 %8, %32, off offset:512\n\t"                       \
    "global_load_dwordx4 %24, %33, off offset:512\n\t"                      \
    "global_load_dwordx4 %9, %32, off offset:576\n\t"                       \
    "global_load_dwordx4 %25, %33, off offset:576\n\t"                      \
    "global_load_dwordx4 %10, %32, off offset:640\n\t"                      \
    "global_load_dwordx4 %26, %33, off offset:640\n\t"                      \
    "global_load_dwordx4 %11, %32, off offset:704\n\t"                      \
    "global_load_dwordx4 %27, %33, off offset:704\n\t"                      \
    "global_load_dwordx4 %12, %32, off offset:768\n\t"                      \
    "global_load_dwordx4 %28, %33, off offset:768\n\t"                      \
    "global_load_dwordx4 %13, %32, off offset:832\n\t"                      \
    "global_load_dwordx4 %29, %33, off offset:832\n\t"                      \
    "global_load_dwordx4 %14, %32, off offset:896\n\t"                      \
    "global_load_dwordx4 %30, %33, off offset:896\n\t"                      \
    "global_load_dwordx4 %15, %32, off offset:960\n\t"                      \
    "global_load_dwordx4 %31, %33, off offset:960\n\t"                      \
    "s_waitcnt vmcnt(0)"                                                    \
    : "=&v"(f[0]), "=&v"(f[1]), "=&v"(f[2]), "=&v"(f[3]),                   \
      "=&v"(f[4]), "=&v"(f[5]), "=&v"(f[6]), "=&v"(f[7]),                   \
      "=&v"(f[8]), "=&v"(f[9]), "=&v"(f[10]), "=&v"(f[11]),                 \
      "=&v"(f[12]), "=&v"(f[13]), "=&v"(f[14]), "=&v"(f[15]),               \
      "=&v"(g[0]), "=&v"(g[1]), "=&v"(g[2]), "=&v"(g[3]),                   \
      "=&v"(g[4]), "=&v"(g[5]), "=&v"(g[6]), "=&v"(g[7]),                   \
      "=&v"(g[8]), "=&v"(g[9]), "=&v"(g[10]), "=&v"(g[11]),                 \
      "=&v"(g[12]), "=&v"(g[13]), "=&v"(g[14]), "=&v"(g[15])                \
    : "v"(p0), "v"(p1) : "memory")

#define WAITVM asm volatile("s_waitcnt vmcnt(0)" ::: "memory")

// ---- prep: fp32->bf16 conversions, bias sums, flag zeroing ----
__global__ void k_prep(const float* __restrict__ x,
                       const float* __restrict__ w0ih, const float* __restrict__ w0hh,
                       const float* __restrict__ b0i,  const float* __restrict__ b0h,
                       const float* __restrict__ w1ih, const float* __restrict__ w1hh,
                       const float* __restrict__ b1i,  const float* __restrict__ b1h,
                       u16* __restrict__ xb,
                       u16* __restrict__ w0ihb, u16* __restrict__ w0hhb,
                       u16* __restrict__ w1ihb, u16* __restrict__ w1hhb,
                       float* __restrict__ bias0, float* __restrict__ bias1,
                       int* __restrict__ flags)
{
    const int stride = gridDim.x * blockDim.x;
    const int tid = blockIdx.x * blockDim.x + threadIdx.x;
    for (int i = tid; i < M_TOT * H_D / 4; i += stride) {
        const float4 v = ((const float4*)x)[i];
        ushort4 o;
        o.x = f2bf(v.x); o.y = f2bf(v.y); o.z = f2bf(v.z); o.w = f2bf(v.w);
        ((ushort4*)xb)[i] = o;
    }
    for (int i = tid; i < H_D * H_D; i += stride) {
        w0ihb[i] = f2bf(w0ih[i]);
        w0hhb[i] = f2bf(w0hh[i]);
        w1ihb[i] = f2bf(w1ih[i]);
        w1hhb[i] = f2bf(w1hh[i]);
    }
    if (tid < H_D) {
        bias0[tid] = b0i[tid] + b0h[tid];
        bias1[tid] = b1i[tid] + b1h[tid];
    }
    if (tid < 192) flags[tid] = 0;
}

// ---- big parallel GEMM: out[M,512] = A @ W^T + bias (bf16 MFMA) ----
__global__ __launch_bounds__(256)
void k_gemm(const u16* __restrict__ A, const u16* __restrict__ W,
            const float* __restrict__ bias, float* __restrict__ out)
{
    __shared__ u16 As[128][40];
    __shared__ u16 Ws[128][40];
    const int m0 = blockIdx.x * 128;
    const int n0 = blockIdx.y * 128;
    const int tid = threadIdx.x;
    const int w = tid >> 6, l = tid & 63, q = l >> 4, lr = l & 15;
    const int mw = (w >> 1) * 64, nw = (w & 1) * 64;
    const int skg = (tid & 3) * 8;
    const int smr = tid >> 2;

    f32x4 acc[4][4];
    #pragma unroll
    for (int i = 0; i < 4; ++i)
        #pragma unroll
        for (int j = 0; j < 4; ++j)
            acc[i][j] = (f32x4){0.f, 0.f, 0.f, 0.f};

    for (int kk = 0; kk < H_D; kk += 32) {
        *(uint4*)&As[smr][skg]      = *(const uint4*)(A + (size_t)(m0 + smr) * H_D + kk + skg);
        *(uint4*)&As[smr + 64][skg] = *(const uint4*)(A + (size_t)(m0 + smr + 64) * H_D + kk + skg);
        *(uint4*)&Ws[smr][skg]      = *(const uint4*)(W + (size_t)(n0 + smr) * H_D + kk + skg);
        *(uint4*)&Ws[smr + 64][skg] = *(const uint4*)(W + (size_t)(n0 + smr + 64) * H_D + kk + skg);
        __syncthreads();
        short8 af[4], bf[4];
        #pragma unroll
        for (int rt = 0; rt < 4; ++rt) af[rt] = *(const short8*)&As[mw + rt*16 + lr][q*8];
        #pragma unroll
        for (int nt = 0; nt < 4; ++nt) bf[nt] = *(const short8*)&Ws[nw + nt*16 + lr][q*8];
        #pragma unroll
        for (int rt = 0; rt < 4; ++rt)
            #pragma unroll
            for (int nt = 0; nt < 4; ++nt)
                acc[rt][nt] = __builtin_amdgcn_mfma_f32_16x16x32_bf16(af[rt], bf[nt], acc[rt][nt], 0, 0, 0);
        __syncthreads();
    }
    #pragma unroll
    for (int nt = 0; nt < 4; ++nt) {
        const int col = n0 + nw + nt*16 + lr;
        const float bv = bias[col];
        #pragma unroll
        for (int rt = 0; rt < 4; ++rt) {
            #pragma unroll
            for (int r = 0; r < 4; ++r) {
                const int row = m0 + mw + rt*16 + q*4 + r;
                out[(size_t)row * H_D + col] = acc[rt][nt][r] + bv;
            }
        }
    }
}

// ---- fused 2-layer recurrence, pipelined across layers ----
// blocks 0..15: layer 0 (32-col slices).  blocks 16..47: layer 1 (16-col slices).
// hbuf slot s holds h[t = s-1]; slot 0 = h_init.
// flags0[c] (16 words) / flags1[c] (32 words): per-BLOCK published-slot count.
// Only wave 0 of each block polls (s_sleep backoff), then releases via barrier
// -> 48 polling waves instead of 192 (cuts L3 flag-line contention).
// MFMA operands are SWAPPED (W-frag first): lane (q,lr) accumulates batch-row
// r0+lr, 4 consecutive cols nbase+q*4+r -> h stores are dwordx2, pre0/out/hn
// are float4.
__global__ __launch_bounds__(256, 1)
void k_rec_fused(const u16* __restrict__ Whh0, const u16* __restrict__ Wih1,
                 const u16* __restrict__ Whh1,
                 const float* __restrict__ h_init,
                 const float* __restrict__ pre0,
                 const float* __restrict__ bias1,
                 u16* __restrict__ h0buf, u16* __restrict__ h1buf,
                 float* __restrict__ out, float* __restrict__ hn,
                 int* __restrict__ flags0, int* __restrict__ flags1)
{
    // One-shot agent-scope acquire: invalidate L1 + XCD-L2 so no stale
    // pre-kernel line can satisfy our cached h loads.
    (void)__hip_atomic_load(flags0, __ATOMIC_ACQUIRE, __HIP_MEMORY_SCOPE_AGENT);

    const int tid = threadIdx.x;
    const int w = tid >> 6, l = tid & 63, q = l >> 4, lr = l & 15;
    const int r0 = w * 16;
    const int m = r0 + lr;

    if (blockIdx.x < 16) {
        // ================= layer 0: 32 columns =================
        const int c = blockIdx.x;
        const int nbase = c * 32;
        short8 breg[16][2];
        #pragma unroll
        for (int kt = 0; kt < 16; ++kt)
            #pragma unroll
            for (int nt = 0; nt < 2; ++nt)
                breg[kt][nt] = *(const short8*)(Whh0 + (size_t)(nbase + nt*16 + lr) * H_D + kt*32 + q*8);

        // stage 0: publish h_init slot 0 (our 16 rows x 32 cols)
        #pragma unroll
        for (int j = 0; j < 8; ++j) {
            int idx = l * 8 + j;
            int row = r0 + (idx >> 5);
            int col = nbase + (idx & 31);
            st_h(h0buf + (size_t)row * H_D + col, f2bf(h_init[row * H_D + col]));
        }
        WAITVM;
        __syncthreads();
        if (tid == 0) st_flag(flags0 + c, 1);

        for (int t = 0; t < L_SEQ; ++t) {
            // pre-activation init (independent of flags): one float4 x2
            const float* pt = pre0 + (size_t)t * (N_B * H_D)
                            + (size_t)(r0 + lr) * H_D + nbase + q*4;
            f32x4 acc0a = *(const f32x4*)pt;
            f32x4 acc1a = *(const f32x4*)(pt + 16);
            f32x4 acc0b = (f32x4){0.f,0.f,0.f,0.f};
            f32x4 acc1b = (f32x4){0.f,0.f,0.f,0.f};

            if (w == 0) {
                const int* p = flags0 + (l & 15);
                while (true) {
                    int v = __hip_atomic_load(p, __ATOMIC_RELAXED, __HIP_MEMORY_SCOPE_AGENT);
                    if (__all(v >= t + 1)) break;
                    __builtin_amdgcn_s_sleep(1);
                }
                asm volatile("" ::: "memory");
            }
            __syncthreads();

            const u16* hs = h0buf + ((size_t)t * N_B + m) * H_D + q*8;
            i32x4 f[16];
            LD16(f, hs);
            #pragma unroll
            for (int kt = 0; kt < 16; kt += 2) {
                acc0a = __builtin_amdgcn_mfma_f32_16x16x32_bf16(breg[kt][0],   __builtin_bit_cast(short8, f[kt]),   acc0a, 0, 0, 0);
                acc1a = __builtin_amdgcn_mfma_f32_16x16x32_bf16(breg[kt][1],   __builtin_bit_cast(short8, f[kt]),   acc1a, 0, 0, 0);
                acc0b = __builtin_amdgcn_mfma_f32_16x16x32_bf16(breg[kt+1][0], __builtin_bit_cast(short8, f[kt+1]), acc0b, 0, 0, 0);
                acc1b = __builtin_amdgcn_mfma_f32_16x16x32_bf16(breg[kt+1][1], __builtin_bit_cast(short8, f[kt+1]), acc1b, 0, 0, 0);
            }
            float v0[4], v1[4];
            #pragma unroll
            for (int r = 0; r < 4; ++r) {
                v0[r] = fast_tanh(acc0a[r] + acc0b[r]);
                v1[r] = fast_tanh(acc1a[r] + acc1b[r]);
            }
            i32x2 d0, d1;
            d0[0] = (int)((unsigned)f2bf(v0[0]) | ((unsigned)f2bf(v0[1]) << 16));
            d0[1] = (int)((unsigned)f2bf(v0[2]) | ((unsigned)f2bf(v0[3]) << 16));
            d1[0] = (int)((unsigned)f2bf(v1[0]) | ((unsigned)f2bf(v1[1]) << 16));
            d1[1] = (int)((unsigned)f2bf(v1[2]) | ((unsigned)f2bf(v1[3]) << 16));
            u16* hd = h0buf + (size_t)(t+1) * (N_B * H_D)
                    + (size_t)(r0 + lr) * H_D + nbase + q*4;
            asm volatile(
                "global_store_dwordx2 %2, %0, off sc1\n\t"
                "global_store_dwordx2 %2, %1, off offset:32 sc1"
                :: "v"(d0), "v"(d1), "v"(hd) : "memory");
            WAITVM;
            __syncthreads();
            if (tid == 0) st_flag(flags0 + c, t + 2);

            if (t == L_SEQ - 1) {
                f32x4 o0 = {v0[0], v0[1], v0[2], v0[3]};
                f32x4 o1 = {v1[0], v1[1], v1[2], v1[3]};
                *(f32x4*)(hn + (size_t)(r0 + lr) * H_D + nbase + q*4)      = o0;
                *(f32x4*)(hn + (size_t)(r0 + lr) * H_D + nbase + 16 + q*4) = o1;
            }
        }
    } else {
        // ================= layer 1: 16 columns =================
        const int c = blockIdx.x - 16;
        const int nbase = c * 16;
        short8 bregI[16], bregH[16];
        #pragma unroll
        for (int kt = 0; kt < 16; ++kt) {
            bregI[kt] = *(const short8*)(Wih1 + (size_t)(nbase + lr) * H_D + kt*32 + q*8);
            bregH[kt] = *(const short8*)(Whh1 + (size_t)(nbase + lr) * H_D + kt*32 + q*8);
        }
        const f32x4 bv4 = *(const f32x4*)(bias1 + nbase + q*4);

        const float* hi1 = h_init + N_B * H_D;
        #pragma unroll
        for (int j = 0; j < 4; ++j) {
            int idx = l * 4 + j;
            int row = r0 + (idx >> 4);
            int col = nbase + (idx & 15);
            st_h(h1buf + (size_t)row * H_D + col, f2bf(hi1[row * H_D + col]));
        }
        WAITVM;
        __syncthreads();
        if (tid == 0) st_flag(flags1 + c, 1);

        for (int t = 0; t < L_SEQ; ++t) {
            if (w == 0) {
                const int* p;
                int need;
                if (l < 16)      { p = flags0 + l;        need = t + 2; }
                else if (l < 48) { p = flags1 + (l - 16); need = t + 1; }
                else             { p = flags0;            need = 0;     }
                while (true) {
                    int v = __hip_atomic_load(p, __ATOMIC_RELAXED, __HIP_MEMORY_SCOPE_AGENT);
                    if (__all(v >= need)) break;
                    __builtin_amdgcn_s_sleep(1);
                }
                asm volatile("" ::: "memory");
            }
            __syncthreads();

            const u16* p0 = h0buf + ((size_t)(t+1) * N_B + m) * H_D + q*8;
            const u16* p1 = h1buf + ((size_t)t     * N_B + m) * H_D + q*8;
            i32x4 f[16], g[16];
            LD16X2(f, g, p0, p1);
            f32x4 accA = bv4;
            f32x4 accB = (f32x4){0.f,0.f,0.f,0.f};
            f32x4 accC = (f32x4){0.f,0.f,0.f,0.f};
            f32x4 accD = (f32x4){0.f,0.f,0.f,0.f};
            #pragma unroll
            for (int kt = 0; kt < 16; kt += 2) {
                accA = __builtin_amdgcn_mfma_f32_16x16x32_bf16(bregI[kt],   __builtin_bit_cast(short8, f[kt]),   accA, 0, 0, 0);
                accB = __builtin_amdgcn_mfma_f32_16x16x32_bf16(bregH[kt],   __builtin_bit_cast(short8, g[kt]),   accB, 0, 0, 0);
                accC = __builtin_amdgcn_mfma_f32_16x16x32_bf16(bregI[kt+1], __builtin_bit_cast(short8, f[kt+1]), accC, 0, 0, 0);
                accD = __builtin_amdgcn_mfma_f32_16x16x32_bf16(bregH[kt+1], __builtin_bit_cast(short8, g[kt+1]), accD, 0, 0, 0);
            }
            float v[4];
            #pragma unroll
            for (int r = 0; r < 4; ++r)
                v[r] = fast_tanh(accA[r] + accB[r] + accC[r] + accD[r]);
            i32x2 d;
            d[0] = (int)((unsigned)f2bf(v[0]) | ((unsigned)f2bf(v[1]) << 16));
            d[1] = (int)((unsigned)f2bf(v[2]) | ((unsigned)f2bf(v[3]) << 16));
            u16* hd = h1buf + (size_t)(t+1) * (N_B * H_D)
                    + (size_t)(r0 + lr) * H_D + nbase + q*4;
            asm volatile(
                "global_store_dwordx2 %1, %0, off sc1"
                :: "v"(d), "v"(hd) : "memory");
            WAITVM;
            __syncthreads();
            if (tid == 0) st_flag(flags1 + c, t + 2);

            f32x4 ov = {v[0], v[1], v[2], v[3]};
            *(f32x4*)(out + (size_t)t * (N_B * H_D)
                      + (size_t)(r0 + lr) * H_D + nbase + q*4) = ov;
            if (t == L_SEQ - 1)
                *(f32x4*)(hn + (size_t)(N_B + r0 + lr) * H_D + nbase + q*4) = ov;
        }
    }
}

extern "C" void kernel_launch(void* const* d_in, const int* in_sizes, int n_in,
                              void* d_out, int out_size, void* d_ws, size_t ws_size,
                              hipStream_t stream)
{
    (void)in_sizes; (void)n_in; (void)out_size; (void)ws_size;
    const float* x    = (const float*)d_in[0];
    const float* h0   = (const float*)d_in[1];
    const float* w0ih = (const float*)d_in[2];
    const float* w0hh = (const float*)d_in[3];
    const float* b0i  = (const float*)d_in[4];
    const float* b0h  = (const float*)d_in[5];
    const float* w1ih = (const float*)d_in[6];
    const float* w1hh = (const float*)d_in[7];
    const float* b1i  = (const float*)d_in[8];
    const float* b1h  = (const float*)d_in[9];
    float* out = (float*)d_out;
    float* hn  = out + (size_t)M_TOT * H_D;

    char* ws = (char*)d_ws;
    size_t off = 0;
    u16* w0ihb = (u16*)(ws + off);   off += (size_t)H_D * H_D * 2;
    u16* w0hhb = (u16*)(ws + off);   off += (size_t)H_D * H_D * 2;
    u16* w1ihb = (u16*)(ws + off);   off += (size_t)H_D * H_D * 2;
    u16* w1hhb = (u16*)(ws + off);   off += (size_t)H_D * H_D * 2;
    float* bias0 = (float*)(ws + off); off += H_D * 4;
    float* bias1 = (float*)(ws + off); off += H_D * 4;
    int* flags   = (int*)(ws + off);   off += 256 * 4;
    int* flags0  = flags;        // 16 words (one per layer-0 block)
    int* flags1  = flags + 64;   // 32 words (one per layer-1 block)
    u16* h0buf   = (u16*)(ws + off);   off += (size_t)(L_SEQ + 1) * N_B * H_D * 2;
    float* pre0  = (float*)(ws + off); off += (size_t)M_TOT * H_D * 4;
    u16* h1buf   = (u16*)(ws + off);   off += (size_t)(L_SEQ + 1) * N_B * H_D * 2;
    u16* xb      = h1buf;   // xb dead after k_gemm; aliases h1buf

    k_prep<<<2048, 256, 0, stream>>>(x, w0ih, w0hh, b0i, b0h, w1ih, w1hh, b1i, b1h,
                                     xb, w0ihb, w0hhb, w1ihb, w1hhb,
                                     bias0, bias1, flags);
    k_gemm<<<dim3(M_TOT/128, H_D/128), 256, 0, stream>>>(xb, w0ihb, bias0, pre0);
    k_rec_fused<<<48, 256, 0, stream>>>(w0hhb, w1ihb, w1hhb, h0, pre0, bias1,
                                        h0buf, h1buf, out, hn, flags0, flags1);
}

// Round 3
// 2935.475 us; speedup vs baseline: 1.3063x; 1.0383x over previous
//
#include <hip/hip_runtime.h>
#include <hip/hip_bf16.h>
#include <math.h>

#define L_SEQ 512
#define N_B   64
#define H_D   512
#define M_TOT (L_SEQ * N_B)   // 32768

typedef unsigned short u16;
typedef unsigned long long u64;
typedef __attribute__((ext_vector_type(8))) short short8;
typedef __attribute__((ext_vector_type(4))) float f32x4;
typedef __attribute__((ext_vector_type(4))) int i32x4;
typedef __attribute__((ext_vector_type(2))) int i32x2;

__device__ __forceinline__ u16 f2bf(float f) {
    unsigned int u = __builtin_bit_cast(unsigned int, f);
    u = u + 0x7fffu + ((u >> 16) & 1u);
    return (u16)(u >> 16);
}

__device__ __forceinline__ float fast_tanh(float x) {
    float e = __expf(2.0f * x);
    return 1.0f - 2.0f / (e + 1.0f);
}

__device__ __forceinline__ void st_h(u16* p, u16 v) {
    __hip_atomic_store(p, v, __ATOMIC_RELAXED, __HIP_MEMORY_SCOPE_AGENT);
}
__device__ __forceinline__ void st_flag(int* p, int v) {
    __hip_atomic_store(p, v, __ATOMIC_RELAXED, __HIP_MEMORY_SCOPE_AGENT);
}

// Flags are spread ONE PER 64B CACHE LINE (stride 16 ints): 16 lines for
// layer-0 blocks, 32 for layer-1 blocks. This kills the same-line
// serialization of (16 sc1 writers + 48 polling waves) that congested the
// coherence point when all flags shared one line.
#define FSTRIDE 16

// 16 CACHED 16B loads (512B of one row) + single drain.
// Correctness of cached loads: h slots are write-once (sc1 write-through to
// the coherence point), consumers first touch a slot's lines only after the
// per-block flag trips, and slot lines are 64B-pure. Entry acquire fence
// kills pre-kernel stale lines (incl. the xb/h1buf alias from k_gemm).
#define LD16(f, p)                                                          \
  asm volatile(                                                             \
    "global_load_dwordx4 %0, %16, off\n\t"                                  \
    "global_load_dwordx4 %1, %16, off offset:64\n\t"                        \
    "global_load_dwordx4 %2, %16, off offset:128\n\t"                       \
    "global_load_dwordx4 %3, %16, off offset:192\n\t"                       \
    "global_load_dwordx4 %4, %16, off offset:256\n\t"                       \
    "global_load_dwordx4 %5, %16, off offset:320\n\t"                       \
    "global_load_dwordx4 %6, %16, off offset:384\n\t"                       \
    "global_load_dwordx4 %7, %16, off offset:448\n\t"                       \
    "global_load_dwordx4 %8, %16, off offset:512\n\t"                       \
    "global_load_dwordx4 %9, %16, off offset:576\n\t"                       \
    "global_load_dwordx4 %10, %16, off offset:640\n\t"                      \
    "global_load_dwordx4 %11, %16, off offset:704\n\t"                      \
    "global_load_dwordx4 %12, %16, off offset:768\n\t"                      \
    "global_load_dwordx4 %13, %16, off offset:832\n\t"                      \
    "global_load_dwordx4 %14, %16, off offset:896\n\t"                      \
    "global_load_dwordx4 %15, %16, off offset:960\n\t"                      \
    "s_waitcnt vmcnt(0)"                                                    \
    : "=&v"(f[0]), "=&v"(f[1]), "=&v"(f[2]), "=&v"(f[3]),                   \
      "=&v"(f[4]), "=&v"(f[5]), "=&v"(f[6]), "=&v"(f[7]),                   \
      "=&v"(f[8]), "=&v"(f[9]), "=&v"(f[10]), "=&v"(f[11]),                 \
      "=&v"(f[12]), "=&v"(f[13]), "=&v"(f[14]), "=&v"(f[15])                \
    : "v"(p) : "memory")

// 32 cached loads from two rows in one batch (layer 1), single drain
#define LD16X2(f, g, p0, p1)                                                \
  asm volatile(                                                             \
    "global_load_dwordx4 %0, %32, off\n\t"                                  \
    "global_load_dwordx4 %16, %33, off\n\t"                                 \
    "global_load_dwordx4 %1, %32, off offset:64\n\t"                        \
    "global_load_dwordx4 %17, %33, off offset:64\n\t"                       \
    "global_load_dwordx4 %2, %32, off offset:128\n\t"                       \
    "global_load_dwordx4 %18, %33, off offset:128\n\t"                      \
    "global_load_dwordx4 %3, %32, off offset:192\n\t"                       \
    "global_load_dwordx4 %19, %33, off offset:192\n\t"                      \
    "global_load_dwordx4 %4, %32, off offset:256\n\t"                       \
    "global_load_dwordx4 %20, %33, off offset:256\n\t"                      \
    "global_load_dwordx4 %5, %32, off offset:320\n\t"                       \
    "global_load_dwordx4 %21, %33, off offset:320\n\t"                      \
    "global_load_dwordx4 %6, %32, off offset:384\n\t"                       \
    "global_load_dwordx4 %22, %33, off offset:384\n\t"                      \
    "global_load_dwordx4 %7, %32, off offset:448\n\t"                       \
    "global_load_dwordx4 %23, %33, off offset:448\n\t"                      \
    "global_load_dwordx4 %8, %32, off offset:512\n\t"                       \
    "global_load_dwordx4 %24, %33, off offset:512\n\t"                      \
    "global_load_dwordx4 %9, %32, off offset:576\n\t"                       \
    "global_load_dwordx4 %25, %33, off offset:576\n\t"                      \
    "global_load_dwordx4 %10, %32, off offset:640\n\t"                      \
    "global_load_dwordx4 %26, %33, off offset:640\n\t"                      \
    "global_load_dwordx4 %11, %32, off offset:704\n\t"                      \
    "global_load_dwordx4 %27, %33, off offset:704\n\t"                      \
    "global_load_dwordx4 %12, %32, off offset:768\n\t"                      \
    "global_load_dwordx4 %28, %33, off offset:768\n\t"                      \
    "global_load_dwordx4 %13, %32, off offset:832\n\t"                      \
    "global_load_dwordx4 %29, %33, off offset:832\n\t"                      \
    "global_load_dwordx4 %14, %32, off offset:896\n\t"                      \
    "global_load_dwordx4 %30, %33, off offset:896\n\t"                      \
    "global_load_dwordx4 %15, %32, off offset:960\n\t"                      \
    "global_load_dwordx4 %31, %33, off offset:960\n\t"                      \
    "s_waitcnt vmcnt(0)"                                                    \
    : "=&v"(f[0]), "=&v"(f[1]), "=&v"(f[2]), "=&v"(f[3]),                   \
      "=&v"(f[4]), "=&v"(f[5]), "=&v"(f[6]), "=&v"(f[7]),                   \
      "=&v"(f[8]), "=&v"(f[9]), "=&v"(f[10]), "=&v"(f[11]),                 \
      "=&v"(f[12]), "=&v"(f[13]), "=&v"(f[14]), "=&v"(f[15]),               \
      "=&v"(g[0]), "=&v"(g[1]), "=&v"(g[2]), "=&v"(g[3]),                   \
      "=&v"(g[4]), "=&v"(g[5]), "=&v"(g[6]), "=&v"(g[7]),                   \
      "=&v"(g[8]), "=&v"(g[9]), "=&v"(g[10]), "=&v"(g[11]),                 \
      "=&v"(g[12]), "=&v"(g[13]), "=&v"(g[14]), "=&v"(g[15])                \
    : "v"(p0), "v"(p1) : "memory")

#define WAITVM asm volatile("s_waitcnt vmcnt(0)" ::: "memory")

// K-permutation within each 32-col block: storage position j holds
// canonical column perm32(j). Lets a layer-0 lane store its 8 output bf16
// (4 cols from each of the two 16-wide MFMA tiles) as ONE dwordx4.
__device__ __host__ __forceinline__ int perm32(int j) {
    return (((j >> 3) & 3) << 2) | (j & 3) | (((j >> 2) & 1) << 4);
}

// ---- prep: fp32->bf16 conversions, bias sums, flag zeroing ----
// w0hhb and w1ihb are stored with their K-dim permuted by perm32 (they
// multiply h0, which is stored position-permuted). w0ihb (k_gemm, canonical
// xb) and w1hhb (multiplies canonical h1buf) stay canonical.
__global__ void k_prep(const float* __restrict__ x,
                       const float* __restrict__ w0ih, const float* __restrict__ w0hh,
                       const float* __restrict__ b0i,  const float* __restrict__ b0h,
                       const float* __restrict__ w1ih, const float* __restrict__ w1hh,
                       const float* __restrict__ b1i,  const float* __restrict__ b1h,
                       u16* __restrict__ xb,
                       u16* __restrict__ w0ihb, u16* __restrict__ w0hhb,
                       u16* __restrict__ w1ihb, u16* __restrict__ w1hhb,
                       float* __restrict__ bias0, float* __restrict__ bias1,
                       int* __restrict__ flags)
{
    const int stride = gridDim.x * blockDim.x;
    const int tid = blockIdx.x * blockDim.x + threadIdx.x;
    for (int i = tid; i < M_TOT * H_D / 4; i += stride) {
        const float4 v = ((const float4*)x)[i];
        ushort4 o;
        o.x = f2bf(v.x); o.y = f2bf(v.y); o.z = f2bf(v.z); o.w = f2bf(v.w);
        ((ushort4*)xb)[i] = o;
    }
    for (int i = tid; i < H_D * H_D; i += stride) {
        const int p  = i & (H_D - 1);
        const int pc = (i & ~(H_D - 1)) | (p & ~31) | perm32(p & 31);
        w0ihb[i] = f2bf(w0ih[i]);
        w0hhb[i] = f2bf(w0hh[pc]);
        w1ihb[i] = f2bf(w1ih[pc]);
        w1hhb[i] = f2bf(w1hh[i]);
    }
    if (tid < H_D) {
        bias0[tid] = b0i[tid] + b0h[tid];
        bias1[tid] = b1i[tid] + b1h[tid];
    }
    if (tid < 48 * FSTRIDE) flags[tid] = 0;
}

// ---- big parallel GEMM: out[M,512] = A @ W^T + bias (bf16 MFMA) ----
__global__ __launch_bounds__(256)
void k_gemm(const u16* __restrict__ A, const u16* __restrict__ W,
            const float* __restrict__ bias, float* __restrict__ out)
{
    __shared__ u16 As[128][40];
    __shared__ u16 Ws[128][40];
    const int m0 = blockIdx.x * 128;
    const int n0 = blockIdx.y * 128;
    const int tid = threadIdx.x;
    const int w = tid >> 6, l = tid & 63, q = l >> 4, lr = l & 15;
    const int mw = (w >> 1) * 64, nw = (w & 1) * 64;
    const int skg = (tid & 3) * 8;
    const int smr = tid >> 2;

    f32x4 acc[4][4];
    #pragma unroll
    for (int i = 0; i < 4; ++i)
        #pragma unroll
        for (int j = 0; j < 4; ++j)
            acc[i][j] = (f32x4){0.f, 0.f, 0.f, 0.f};

    for (int kk = 0; kk < H_D; kk += 32) {
        *(uint4*)&As[smr][skg]      = *(const uint4*)(A + (size_t)(m0 + smr) * H_D + kk + skg);
        *(uint4*)&As[smr + 64][skg] = *(const uint4*)(A + (size_t)(m0 + smr + 64) * H_D + kk + skg);
        *(uint4*)&Ws[smr][skg]      = *(const uint4*)(W + (size_t)(n0 + smr) * H_D + kk + skg);
        *(uint4*)&Ws[smr + 64][skg] = *(const uint4*)(W + (size_t)(n0 + smr + 64) * H_D + kk + skg);
        __syncthreads();
        short8 af[4], bf[4];
        #pragma unroll
        for (int rt = 0; rt < 4; ++rt) af[rt] = *(const short8*)&As[mw + rt*16 + lr][q*8];
        #pragma unroll
        for (int nt = 0; nt < 4; ++nt) bf[nt] = *(const short8*)&Ws[nw + nt*16 + lr][q*8];
        #pragma unroll
        for (int rt = 0; rt < 4; ++rt)
            #pragma unroll
            for (int nt = 0; nt < 4; ++nt)
                acc[rt][nt] = __builtin_amdgcn_mfma_f32_16x16x32_bf16(af[rt], bf[nt], acc[rt][nt], 0, 0, 0);
        __syncthreads();
    }
    #pragma unroll
    for (int nt = 0; nt < 4; ++nt) {
        const int col = n0 + nw + nt*16 + lr;
        const float bv = bias[col];
        #pragma unroll
        for (int rt = 0; rt < 4; ++rt) {
            #pragma unroll
            for (int r = 0; r < 4; ++r) {
                const int row = m0 + mw + rt*16 + q*4 + r;
                out[(size_t)row * H_D + col] = acc[rt][nt][r] + bv;
            }
        }
    }
}

// ---- fused 2-layer recurrence, pipelined across layers ----
// blocks 0..15: layer 0 (32-col slices).  blocks 16..47: layer 1 (16-col slices).
// hbuf slot s holds h[t = s-1]; slot 0 = h_init.
// flags0[c*16] / flags1[c*16]: per-BLOCK published-slot count, one per line.
// Only wave 0 of each block polls, then releases via barrier.
// h0buf rows are position-permuted (perm32 within each 32-col block) so a
// layer-0 lane stores ONE dwordx4 (16 full 64B lines per wave-store).
__global__ __launch_bounds__(256, 1)
void k_rec_fused(const u16* __restrict__ Whh0, const u16* __restrict__ Wih1,
                 const u16* __restrict__ Whh1,
                 const float* __restrict__ h_init,
                 const float* __restrict__ pre0,
                 const float* __restrict__ bias1,
                 u16* __restrict__ h0buf, u16* __restrict__ h1buf,
                 float* __restrict__ out, float* __restrict__ hn,
                 int* __restrict__ flags0, int* __restrict__ flags1)
{
    // One-shot agent-scope acquire: invalidate L1 + XCD-L2 so no stale
    // pre-kernel line can satisfy our cached h loads.
    (void)__hip_atomic_load(flags0, __ATOMIC_ACQUIRE, __HIP_MEMORY_SCOPE_AGENT);

    const int tid = threadIdx.x;
    const int w = tid >> 6, l = tid & 63, q = l >> 4, lr = l & 15;
    const int r0 = w * 16;
    const int m = r0 + lr;

    if (blockIdx.x < 16) {
        // ================= layer 0: 32 columns =================
        const int c = blockIdx.x;
        const int nbase = c * 32;
        short8 breg[16][2];
        #pragma unroll
        for (int kt = 0; kt < 16; ++kt)
            #pragma unroll
            for (int nt = 0; nt < 2; ++nt)
                breg[kt][nt] = *(const short8*)(Whh0 + (size_t)(nbase + nt*16 + lr) * H_D + kt*32 + q*8);

        // stage 0: publish h_init slot 0 (our 16 rows x 32 positions, permuted)
        #pragma unroll
        for (int j = 0; j < 8; ++j) {
            int idx = l * 8 + j;
            int row = r0 + (idx >> 5);
            int pos = idx & 31;
            st_h(h0buf + (size_t)row * H_D + nbase + pos,
                 f2bf(h_init[row * H_D + nbase + perm32(pos)]));
        }
        WAITVM;
        __syncthreads();
        if (tid == 0) st_flag(flags0 + c * FSTRIDE, 1);

        for (int t = 0; t < L_SEQ; ++t) {
            // pre-activation init (independent of flags): one float4 x2
            const float* pt = pre0 + (size_t)t * (N_B * H_D)
                            + (size_t)(r0 + lr) * H_D + nbase + q*4;
            f32x4 acc0a = *(const f32x4*)pt;
            f32x4 acc1a = *(const f32x4*)(pt + 16);
            f32x4 acc0b = (f32x4){0.f,0.f,0.f,0.f};
            f32x4 acc1b = (f32x4){0.f,0.f,0.f,0.f};
            f32x4 acc0c = (f32x4){0.f,0.f,0.f,0.f};
            f32x4 acc1c = (f32x4){0.f,0.f,0.f,0.f};
            f32x4 acc0d = (f32x4){0.f,0.f,0.f,0.f};
            f32x4 acc1d = (f32x4){0.f,0.f,0.f,0.f};

            if (w == 0) {
                const int* p = flags0 + (l & 15) * FSTRIDE;
                while (true) {
                    int v = __hip_atomic_load(p, __ATOMIC_RELAXED, __HIP_MEMORY_SCOPE_AGENT);
                    if (__all(v >= t + 1)) break;
                }
                asm volatile("" ::: "memory");
            }
            __syncthreads();

            const u16* hs = h0buf + ((size_t)t * N_B + m) * H_D + q*8;
            i32x4 f[16];
            LD16(f, hs);
            #pragma unroll
            for (int kt = 0; kt < 16; kt += 4) {
                acc0a = __builtin_amdgcn_mfma_f32_16x16x32_bf16(breg[kt][0],   __builtin_bit_cast(short8, f[kt]),   acc0a, 0, 0, 0);
                acc1a = __builtin_amdgcn_mfma_f32_16x16x32_bf16(breg[kt][1],   __builtin_bit_cast(short8, f[kt]),   acc1a, 0, 0, 0);
                acc0b = __builtin_amdgcn_mfma_f32_16x16x32_bf16(breg[kt+1][0], __builtin_bit_cast(short8, f[kt+1]), acc0b, 0, 0, 0);
                acc1b = __builtin_amdgcn_mfma_f32_16x16x32_bf16(breg[kt+1][1], __builtin_bit_cast(short8, f[kt+1]), acc1b, 0, 0, 0);
                acc0c = __builtin_amdgcn_mfma_f32_16x16x32_bf16(breg[kt+2][0], __builtin_bit_cast(short8, f[kt+2]), acc0c, 0, 0, 0);
                acc1c = __builtin_amdgcn_mfma_f32_16x16x32_bf16(breg[kt+2][1], __builtin_bit_cast(short8, f[kt+2]), acc1c, 0, 0, 0);
                acc0d = __builtin_amdgcn_mfma_f32_16x16x32_bf16(breg[kt+3][0], __builtin_bit_cast(short8, f[kt+3]), acc0d, 0, 0, 0);
                acc1d = __builtin_amdgcn_mfma_f32_16x16x32_bf16(breg[kt+3][1], __builtin_bit_cast(short8, f[kt+3]), acc1d, 0, 0, 0);
            }
            float v0[4], v1[4];
            #pragma unroll
            for (int r = 0; r < 4; ++r) {
                v0[r] = fast_tanh((acc0a[r] + acc0b[r]) + (acc0c[r] + acc0d[r]));
                v1[r] = fast_tanh((acc1a[r] + acc1b[r]) + (acc1c[r] + acc1d[r]));
            }
            // permuted pack: positions q*8+s hold cols q*4+(s&3)+16*(s>>2)
            i32x4 dd;
            dd[0] = (int)((unsigned)f2bf(v0[0]) | ((unsigned)f2bf(v0[1]) << 16));
            dd[1] = (int)((unsigned)f2bf(v0[2]) | ((unsigned)f2bf(v0[3]) << 16));
            dd[2] = (int)((unsigned)f2bf(v1[0]) | ((unsigned)f2bf(v1[1]) << 16));
            dd[3] = (int)((unsigned)f2bf(v1[2]) | ((unsigned)f2bf(v1[3]) << 16));
            u16* hd = h0buf + (size_t)(t+1) * (N_B * H_D)
                    + (size_t)(r0 + lr) * H_D + nbase + q*8;
            asm volatile(
                "global_store_dwordx4 %1, %0, off sc1"
                :: "v"(dd), "v"(hd) : "memory");
            WAITVM;
            __syncthreads();
            if (tid == 0) st_flag(flags0 + c * FSTRIDE, t + 2);

            if (t == L_SEQ - 1) {
                f32x4 o0 = {v0[0], v0[1], v0[2], v0[3]};
                f32x4 o1 = {v1[0], v1[1], v1[2], v1[3]};
                *(f32x4*)(hn + (size_t)(r0 + lr) * H_D + nbase + q*4)      = o0;
                *(f32x4*)(hn + (size_t)(r0 + lr) * H_D + nbase + 16 + q*4) = o1;
            }
        }
    } else {
        // ================= layer 1: 16 columns =================
        const int c = blockIdx.x - 16;
        const int nbase = c * 16;
        short8 bregI[16], bregH[16];
        #pragma unroll
        for (int kt = 0; kt < 16; ++kt) {
            bregI[kt] = *(const short8*)(Wih1 + (size_t)(nbase + lr) * H_D + kt*32 + q*8);
            bregH[kt] = *(const short8*)(Whh1 + (size_t)(nbase + lr) * H_D + kt*32 + q*8);
        }
        const f32x4 bv4 = *(const f32x4*)(bias1 + nbase + q*4);

        const float* hi1 = h_init + N_B * H_D;
        #pragma unroll
        for (int j = 0; j < 4; ++j) {
            int idx = l * 4 + j;
            int row = r0 + (idx >> 4);
            int col = nbase + (idx & 15);
            st_h(h1buf + (size_t)row * H_D + col, f2bf(hi1[row * H_D + col]));
        }
        WAITVM;
        __syncthreads();
        if (tid == 0) st_flag(flags1 + c * FSTRIDE, 1);

        for (int t = 0; t < L_SEQ; ++t) {
            if (w == 0) {
                const int* p;
                int need;
                if (l < 16)      { p = flags0 + l * FSTRIDE;        need = t + 2; }
                else if (l < 48) { p = flags1 + (l - 16) * FSTRIDE; need = t + 1; }
                else             { p = flags0;                      need = 0;     }
                while (true) {
                    int v = __hip_atomic_load(p, __ATOMIC_RELAXED, __HIP_MEMORY_SCOPE_AGENT);
                    if (__all(v >= need)) break;
                }
                asm volatile("" ::: "memory");
            }
            __syncthreads();

            const u16* p0 = h0buf + ((size_t)(t+1) * N_B + m) * H_D + q*8;
            const u16* p1 = h1buf + ((size_t)t     * N_B + m) * H_D + q*8;
            i32x4 f[16], g[16];
            LD16X2(f, g, p0, p1);
            f32x4 accA = bv4;
            f32x4 accB = (f32x4){0.f,0.f,0.f,0.f};
            f32x4 accC = (f32x4){0.f,0.f,0.f,0.f};
            f32x4 accD = (f32x4){0.f,0.f,0.f,0.f};
            #pragma unroll
            for (int kt = 0; kt < 16; kt += 2) {
                accA = __builtin_amdgcn_mfma_f32_16x16x32_bf16(bregI[kt],   __builtin_bit_cast(short8, f[kt]),   accA, 0, 0, 0);
                accB = __builtin_amdgcn_mfma_f32_16x16x32_bf16(bregH[kt],   __builtin_bit_cast(short8, g[kt]),   accB, 0, 0, 0);
                accC = __builtin_amdgcn_mfma_f32_16x16x32_bf16(bregI[kt+1], __builtin_bit_cast(short8, f[kt+1]), accC, 0, 0, 0);
                accD = __builtin_amdgcn_mfma_f32_16x16x32_bf16(bregH[kt+1], __builtin_bit_cast(short8, g[kt+1]), accD, 0, 0, 0);
            }
            float v[4];
            #pragma unroll
            for (int r = 0; r < 4; ++r)
                v[r] = fast_tanh((accA[r] + accB[r]) + (accC[r] + accD[r]));
            i32x2 d;
            d[0] = (int)((unsigned)f2bf(v[0]) | ((unsigned)f2bf(v[1]) << 16));
            d[1] = (int)((unsigned)f2bf(v[2]) | ((unsigned)f2bf(v[3]) << 16));
            u16* hd = h1buf + (size_t)(t+1) * (N_B * H_D)
                    + (size_t)(r0 + lr) * H_D + nbase + q*4;
            asm volatile(
                "global_store_dwordx2 %1, %0, off sc1"
                :: "v"(d), "v"(hd) : "memory");
            WAITVM;
            __syncthreads();
            if (tid == 0) st_flag(flags1 + c * FSTRIDE, t + 2);

            f32x4 ov = {v[0], v[1], v[2], v[3]};
            *(f32x4*)(out + (size_t)t * (N_B * H_D)
                      + (size_t)(r0 + lr) * H_D + nbase + q*4) = ov;
            if (t == L_SEQ - 1)
                *(f32x4*)(hn + (size_t)(N_B + r0 + lr) * H_D + nbase + q*4) = ov;
        }
    }
}

extern "C" void kernel_launch(void* const* d_in, const int* in_sizes, int n_in,
                              void* d_out, int out_size, void* d_ws, size_t ws_size,
                              hipStream_t stream)
{
    (void)in_sizes; (void)n_in; (void)out_size; (void)ws_size;
    const float* x    = (const float*)d_in[0];
    const float* h0   = (const float*)d_in[1];
    const float* w0ih = (const float*)d_in[2];
    const float* w0hh = (const float*)d_in[3];
    const float* b0i  = (const float*)d_in[4];
    const float* b0h  = (const float*)d_in[5];
    const float* w1ih = (const float*)d_in[6];
    const float* w1hh = (const float*)d_in[7];
    const float* b1i  = (const float*)d_in[8];
    const float* b1h  = (const float*)d_in[9];
    float* out = (float*)d_out;
    float* hn  = out + (size_t)M_TOT * H_D;

    char* ws = (char*)d_ws;
    size_t off = 0;
    u16* w0ihb = (u16*)(ws + off);   off += (size_t)H_D * H_D * 2;
    u16* w0hhb = (u16*)(ws + off);   off += (size_t)H_D * H_D * 2;
    u16* w1ihb = (u16*)(ws + off);   off += (size_t)H_D * H_D * 2;
    u16* w1hhb = (u16*)(ws + off);   off += (size_t)H_D * H_D * 2;
    float* bias0 = (float*)(ws + off); off += H_D * 4;
    float* bias1 = (float*)(ws + off); off += H_D * 4;
    int* flags   = (int*)(ws + off);   off += 48 * FSTRIDE * 4;
    int* flags0  = flags;                  // 16 flags, one per 64B line
    int* flags1  = flags + 16 * FSTRIDE;   // 32 flags, one per 64B line
    u16* h0buf   = (u16*)(ws + off);   off += (size_t)(L_SEQ + 1) * N_B * H_D * 2;
    float* pre0  = (float*)(ws + off); off += (size_t)M_TOT * H_D * 4;
    u16* h1buf   = (u16*)(ws + off);   off += (size_t)(L_SEQ + 1) * N_B * H_D * 2;
    u16* xb      = h1buf;   // xb dead after k_gemm; aliases h1buf

    k_prep<<<2048, 256, 0, stream>>>(x, w0ih, w0hh, b0i, b0h, w1ih, w1hh, b1i, b1h,
                                     xb, w0ihb, w0hhb, w1ihb, w1hhb,
                                     bias0, bias1, flags);
    k_gemm<<<dim3(M_TOT/128, H_D/128), 256, 0, stream>>>(xb, w0ihb, bias0, pre0);
    k_rec_fused<<<48, 256, 0, stream>>>(w0hhb, w1ihb, w1hhb, h0, pre0, bias1,
                                        h0buf, h1buf, out, hn, flags0, flags1);
}